// Round 1
// baseline (592.360 us; speedup 1.0000x reference)
//
#include <hip/hip_runtime.h>
#include <hip/hip_bf16.h>

typedef __bf16 bf8 __attribute__((ext_vector_type(8)));
typedef __bf16 bfx4 __attribute__((ext_vector_type(4)));
typedef float f4 __attribute__((ext_vector_type(4)));

#define NTOK 9216
#define CDIM 256
#define LOG2E 1.44269504f

// ---- MFMA fragment helpers (16x16x32 bf16) --------------------------------
// A[m][k]: lane m=l&15, k=(l>>4)*8+j ; Bt[n][k] same ; D: row=(l>>4)*4+reg,
// col=l&15  [verified by R1/R2 passing]
__device__ inline bf8 ldfrag(const __bf16* p, int ld) {
  int l = threadIdx.x & 63;
  return *reinterpret_cast<const bf8*>(p + (l & 15) * ld + ((l >> 4) << 3));
}
__device__ inline f4 mfma16(bf8 a, bf8 b, f4 c) {
  return __builtin_amdgcn_mfma_f32_16x16x32_bf16(a, b, c, 0, 0, 0);
}
// async global->LDS, 16B per lane; LDS dest = base + lane*16 (wave-uniform base)
__device__ inline void gl2lds(const __bf16* g, __bf16* l) {
  __builtin_amdgcn_global_load_lds(
      (const __attribute__((address_space(1))) void*)g,
      (__attribute__((address_space(3))) void*)l, 16, 0, 0);
}

// ---- generic m97-style GEMM: C[M][N] = A[M][K](lda) x Bt[N][K](ldb)^T ------
// 128x128 tile, BK=32, 4 waves in 2x2. blockIdx.z = split-K part (adds z*K to
// the k offset of both A and Bt; caller passes K = per-part k count).
// EPI: 0 = store fp32, 1 = store bf16, 2 = atomicAdd fp32
template <int EPI>
__global__ __launch_bounds__(256) void gemm128(const __bf16* __restrict__ A, int lda,
                                               const __bf16* __restrict__ Bt, int ldb,
                                               void* __restrict__ Cv, int ldc, int K) {
  __shared__ __bf16 As[128 * 32];
  __shared__ __bf16 Bs[128 * 32];
  const int tid = threadIdx.x;
  const int w = tid >> 6, lane = tid & 63;
  const int lc = lane & 15, quad = lane >> 4;
  const int m0 = blockIdx.x * 128, n0 = blockIdx.y * 128;
  A += (size_t)blockIdx.z * K;
  Bt += (size_t)blockIdx.z * K;
  const int wm = (w & 1) << 6, wn = (w >> 1) << 6;
  // staging: wave w fills LDS chunks 2w, 2w+1 of A and B (16 rows x 32k each)
  const int r0 = (w * 2) * 16 + (lane >> 2);
  const int cg = (lane & 3) * 8;
  const __bf16* gA0 = A + (size_t)(m0 + r0) * lda + cg;
  const __bf16* gA1 = A + (size_t)(m0 + r0 + 16) * lda + cg;
  const __bf16* gB0 = Bt + (size_t)(n0 + r0) * ldb + cg;
  const __bf16* gB1 = Bt + (size_t)(n0 + r0 + 16) * ldb + cg;
  __bf16* lA0 = As + (w * 2) * 512;
  __bf16* lA1 = As + (w * 2 + 1) * 512;
  __bf16* lB0 = Bs + (w * 2) * 512;
  __bf16* lB1 = Bs + (w * 2 + 1) * 512;

  f4 acc[4][4] = {};
  for (int kk = 0; kk < K; kk += 32) {
    __syncthreads();
    gl2lds(gA0 + kk, lA0);
    gl2lds(gA1 + kk, lA1);
    gl2lds(gB0 + kk, lB0);
    gl2lds(gB1 + kk, lB1);
    __syncthreads();  // compiler drains vmcnt before s_barrier
    bf8 af[4], bfr[4];
    for (int i = 0; i < 4; i++) af[i] = ldfrag(As + (wm + 16 * i) * 32, 32);
    for (int j = 0; j < 4; j++) bfr[j] = ldfrag(Bs + (wn + 16 * j) * 32, 32);
    for (int i = 0; i < 4; i++)
      for (int j = 0; j < 4; j++) acc[i][j] = mfma16(af[i], bfr[j], acc[i][j]);
  }
  for (int i = 0; i < 4; i++)
    for (int j = 0; j < 4; j++)
      for (int r = 0; r < 4; r++) {
        size_t idx = (size_t)(m0 + wm + 16 * i + quad * 4 + r) * ldc +
                     (n0 + wn + 16 * j + lc);
        if (EPI == 0) ((float*)Cv)[idx] = acc[i][j][r];
        else if (EPI == 1) ((__bf16*)Cv)[idx] = (__bf16)acc[i][j][r];
        else atomicAdd(((float*)Cv) + idx, acc[i][j][r]);
      }
}

// ---- prep: bf16 weights (Wq pre-scaled by log2e, fused QK), rel gather ----
__global__ __launch_bounds__(256) void prep_kernel(
    const float* Wq, const float* Wk, const float* Wv, const float* embd,
    const float* Wproj, const int* dist, const int* isWithin,
    __bf16* Wqkb, __bf16* Wvb, __bf16* Wpb, float* wl, __bf16* rel) {
  int tid = blockIdx.x * 256 + threadIdx.x;
  if (tid < 65536) {
    Wqkb[tid] = (__bf16)(Wq[tid] * LOG2E);  // rows 0..255: Q (exp2 domain)
    Wqkb[65536 + tid] = (__bf16)Wk[tid];    // rows 256..511: K
    Wvb[tid] = (__bf16)Wv[tid];
    int o = tid >> 8, c = tid & 255;
    Wpb[tid] = (__bf16)Wproj[o * 257 + c];
    if (c == 0) wl[o] = Wproj[o * 257 + 256];
  }
  if (tid < 16 * 256) {
    int z = tid >> 8, c = tid & 255;
    rel[tid] = (__bf16)embd[(isWithin[z] * 17 + dist[z] + 8) * 256 + c];
  }
}

// ---- transpose x [C,N] f32 -> Xt [N,C] bf16 -------------------------------
__global__ __launch_bounds__(256) void transpose_kernel(const float* x, __bf16* Xt) {
  __shared__ __bf16 tile[32][33];
  int n0 = blockIdx.x * 32;
  int c0 = blockIdx.y * 32;
  int tx = threadIdx.x & 31, ty = threadIdx.x >> 5;
  for (int i = 0; i < 32; i += 8)
    tile[ty + i][tx] = (__bf16)x[(c0 + ty + i) * NTOK + n0 + tx];
  __syncthreads();
  for (int i = 0; i < 32; i += 8)
    Xt[(n0 + ty + i) * CDIM + c0 + tx] = tile[tx][ty + i];
}

// ---- pos[16,9216] f32 = rel[16,256] x Xt[9216,256]^T ----------------------
__global__ __launch_bounds__(256) void gemm_pos(const __bf16* rel, const __bf16* Xt,
                                                float* pos) {
  int n0 = blockIdx.x * 256 + (threadIdx.x >> 6) * 64;
  f4 acc[4] = {};
  for (int ks = 0; ks < 256; ks += 32) {
    bf8 a = ldfrag(rel + ks, 256);
    for (int j = 0; j < 4; j++) {
      bf8 b = ldfrag(Xt + (n0 + 16 * j) * 256 + ks, 256);
      acc[j] = mfma16(a, b, acc[j]);
    }
  }
  int l = threadIdx.x & 63, lc = l & 15, quad = l >> 4;
  for (int j = 0; j < 4; j++)
    for (int r = 0; r < 4; r++)
      pos[(quad * 4 + r) * NTOK + n0 + 16 * j + lc] = acc[j][r];
}

__global__ __launch_bounds__(256) void zero_y_kernel(float* Y) {
  reinterpret_cast<f4*>(Y)[blockIdx.x * 256 + threadIdx.x] = f4{0.f, 0.f, 0.f, 0.f};
}

// ---- per-k-row softmax stats over full q (one block per row) --------------
__global__ __launch_bounds__(256) void stats_kernel(const float* S, int kc0,
                                                    float* mArr, float* dinvArr) {
  const float* row = S + (size_t)blockIdx.x * NTOK;
  int t = threadIdx.x, w = t >> 6;
  f4 v[9];
  for (int i = 0; i < 9; i++) v[i] = reinterpret_cast<const f4*>(row)[t + 256 * i];
  float m = -1e30f;
  for (int i = 0; i < 9; i++)
    for (int j = 0; j < 4; j++) m = fmaxf(m, v[i][j]);
  for (int off = 1; off < 64; off <<= 1) m = fmaxf(m, __shfl_xor(m, off));
  __shared__ float wm_[4], wd_[4];
  if ((t & 63) == 0) wm_[w] = m;
  __syncthreads();
  m = fmaxf(fmaxf(wm_[0], wm_[1]), fmaxf(wm_[2], wm_[3]));
  float d = 0.f;
  for (int i = 0; i < 9; i++)
    for (int j = 0; j < 4; j++) d += exp2f(v[i][j] - m);
  for (int off = 1; off < 64; off <<= 1) d += __shfl_xor(d, off);
  if ((t & 63) == 0) wd_[w] = d;
  __syncthreads();
  if (t == 0) {
    mArr[kc0 + blockIdx.x] = m;
    dinvArr[kc0 + blockIdx.x] = 1.0f / (wd_[0] + wd_[1] + wd_[2] + wd_[3]);
  }
}

// ---- P'[q][klocal] = bf16(exp2(S[klocal][q]-m_k)*dinv_k), 64x64 LDS transp -
__global__ __launch_bounds__(256) void pbuild_kernel(const float* S, const float* mArr,
                                                     const float* dinvArr, int kc0,
                                                     __bf16* Pt, int KC) {
  __shared__ float tile[64][65];
  __shared__ float ms[64], ds[64];
  int q0 = blockIdx.x * 64, k0 = blockIdx.y * 64;
  int t = threadIdx.x;
  if (t < 64) {
    ms[t] = mArr[kc0 + k0 + t];
    ds[t] = dinvArr[kc0 + k0 + t];
  }
  int kr = t >> 4, qc = t & 15;
  for (int it = 0; it < 4; it++) {
    int k = kr + it * 16;
    f4 sv = reinterpret_cast<const f4*>(S + (size_t)(k0 + k) * NTOK + q0)[qc];
    for (int j = 0; j < 4; j++) tile[k][qc * 4 + j] = sv[j];
  }
  __syncthreads();
  int qr = t >> 2, ks = (t & 3) * 16;
  bf8 h0, h1;
  for (int i = 0; i < 8; i++) {
    h0[i] = (__bf16)(exp2f(tile[ks + i][qr] - ms[ks + i]) * ds[ks + i]);
    h1[i] = (__bf16)(exp2f(tile[ks + 8 + i][qr] - ms[ks + 8 + i]) * ds[ks + 8 + i]);
  }
  __bf16* dst = Pt + (size_t)(q0 + qr) * KC + k0 + ks;
  *reinterpret_cast<bf8*>(dst) = h0;
  *reinterpret_cast<bf8*>(dst + 8) = h1;
}

// ---- combine Yt + residual -> outT [N,C] bf16 -----------------------------
__global__ __launch_bounds__(256) void combine_y_kernel(const float* Y,
                                                        const __bf16* Xt, __bf16* outT) {
  int i = blockIdx.x * 256 + threadIdx.x;
  f4 y = reinterpret_cast<const f4*>(Y)[i];
  bfx4 xv = reinterpret_cast<const bfx4*>(Xt)[i];
  bfx4 o;
  for (int t = 0; t < 4; t++) o[t] = (__bf16)(y[t] + (float)xv[t]);
  reinterpret_cast<bfx4*>(outT)[i] = o;
}

// ---- final: out[z,o,n] = base[o,n] + wl[o]*pos[z,n] -----------------------
__global__ __launch_bounds__(256) void final_kernel(const float* base, const float* pos,
                                                    const float* wl, float* out) {
  int i = blockIdx.x * 256 + threadIdx.x;
  int n4 = i % 2304;
  int t = i / 2304;
  int o = t & 255;
  int z = t >> 8;
  f4 b = reinterpret_cast<const f4*>(base)[o * 2304 + n4];
  f4 p = reinterpret_cast<const f4*>(pos)[z * 2304 + n4];
  float ww = wl[o];
  f4 r;
  for (int u = 0; u < 4; u++) r[u] = b[u] + ww * p[u];
  reinterpret_cast<f4*>(out)[i] = r;
}

extern "C" void kernel_launch(void* const* d_in, const int* in_sizes, int n_in,
                              void* d_out, int out_size, void* d_ws, size_t ws_size,
                              hipStream_t stream) {
  const float* x = (const float*)d_in[0];
  const float* Wq = (const float*)d_in[1];
  const float* Wk = (const float*)d_in[2];
  const float* Wv = (const float*)d_in[3];
  const float* embd = (const float*)d_in[4];
  const float* Wproj = (const float*)d_in[5];
  const int* dist = (const int*)d_in[6];
  const int* isW = (const int*)d_in[7];
  float* out = (float*)d_out;

  char* w8 = (char*)d_ws;
  __bf16* Xt = (__bf16*)(w8 + 0);            // 4,718,592
  __bf16* QKt = (__bf16*)(w8 + 4718592);     // 9,437,184 [q][512]: Q|K
  __bf16* V = (__bf16*)(w8 + 14155776);      // 4,718,592 [c][n]
  __bf16* Wqkb = (__bf16*)(w8 + 18874368);   // 262,144
  __bf16* Wvb = (__bf16*)(w8 + 19136512);    // 131,072
  __bf16* Wpb = (__bf16*)(w8 + 19267584);    // 131,072
  __bf16* rel = (__bf16*)(w8 + 19398656);    // 8,192
  float* wl = (float*)(w8 + 19406848);       // 1,024
  float* pos = (float*)(w8 + 19407872);      // 589,824
  float* mArr = (float*)(w8 + 19997696);     // 36,864
  float* dinv = (float*)(w8 + 20034560);     // 36,864
  float* Yt = (float*)(w8 + 20071424);       // 9,437,184 [q][c] fp32
  const size_t sOff = 29508608;
  float* S = (float*)(w8 + sOff);            // KC*36,864

  // adaptive chunk size (ws_size constant across calls -> graph-safe)
  static const int KCS[] = {9216, 4608, 2304, 1152, 768, 384, 256};
  int KC = 0;
  for (int i = 0; i < 7; i++) {
    size_t need = sOff + (size_t)KCS[i] * NTOK * 6;  // S fp32 + P' bf16
    if (need <= ws_size) { KC = KCS[i]; break; }
  }
  __bf16* Pt;
  __bf16* outT;
  float* base;
  if (KC) {
    Pt = (__bf16*)(w8 + sOff + (size_t)KC * NTOK * 4);
    outT = (__bf16*)(w8 + sOff);             // alias S (dead by then); >=14.2MB
    base = (float*)(w8 + sOff + 4718592);
  } else {                                   // guaranteed-fit fallback (~50.7MB)
    KC = 128;
    Pt = (__bf16*)(w8 + sOff + (size_t)KC * NTOK * 4);
    outT = (__bf16*)(w8 + sOff + (size_t)KC * NTOK * 6);
    base = (float*)(w8 + sOff + (size_t)KC * NTOK * 6 + 4718592);
  }
  int zk = 1;
  if (KC >= 2304) zk = KC / 1152;
  else if (KC == 1152 || KC == 768) zk = 2;
  const int NC = NTOK / KC;

  prep_kernel<<<256, 256, 0, stream>>>(Wq, Wk, Wv, embd, Wproj, dist, isW,
                                       Wqkb, Wvb, Wpb, wl, rel);
  transpose_kernel<<<dim3(288, 8), 256, 0, stream>>>(x, Xt);
  // QK fused: QKt[9216][512] = Xt x Wqkb^T
  gemm128<1><<<dim3(72, 4), 256, 0, stream>>>(Xt, 256, Wqkb, 256, QKt, 512, 256);
  // V[256][9216] = Wvb x Xt^T
  gemm128<1><<<dim3(2, 72), 256, 0, stream>>>(Wvb, 256, Xt, 256, V, NTOK, 256);
  gemm_pos<<<36, 256, 0, stream>>>(rel, Xt, pos);
  zero_y_kernel<<<2304, 256, 0, stream>>>(Yt);

  for (int c = 0; c < NC; c++) {
    int kc0 = c * KC;
    // S[klocal][q] = Kt_chunk x Qt^T   (fp32, log2 domain)
    gemm128<0><<<dim3(KC / 128, 72), 256, 0, stream>>>(
        QKt + (size_t)kc0 * 512 + 256, 512, QKt, 512, S, NTOK, 256);
    stats_kernel<<<KC, 256, 0, stream>>>(S, kc0, mArr, dinv);
    pbuild_kernel<<<dim3(144, KC / 64), 256, 0, stream>>>(S, mArr, dinv, kc0, Pt, KC);
    // Yt[q][c] += P' x V_chunk^T  (split-K, fp32 atomics)
    gemm128<2><<<dim3(72, 2, zk), 256, 0, stream>>>(Pt, KC, V + kc0, NTOK, Yt, 256,
                                                    KC / zk);
  }
  combine_y_kernel<<<2304, 256, 0, stream>>>(Yt, Xt, outT);
  // base[o][n] = Wpb x outT^T
  gemm128<0><<<dim3(2, 72), 256, 0, stream>>>(Wpb, 256, outT, 256, base, NTOK, 256);
  final_kernel<<<36864, 256, 0, stream>>>(base, pos, wl, out);
}

// Round 2
// 522.620 us; speedup vs baseline: 1.1334x; 1.1334x over previous
//
#include <hip/hip_runtime.h>
#include <hip/hip_bf16.h>

typedef __bf16 bf8 __attribute__((ext_vector_type(8)));
typedef __bf16 bfx4 __attribute__((ext_vector_type(4)));
typedef float f4 __attribute__((ext_vector_type(4)));

#define NTOK 9216
#define CDIM 256
#define LOG2E 1.44269504f

// ---- MFMA fragment helpers (16x16x32 bf16) --------------------------------
// A[m][k]: lane m=l&15, k=(l>>4)*8+j ; Bt[n][k] same ; D: row=(l>>4)*4+reg,
// col=l&15
__device__ inline bf8 ldfrag(const __bf16* p, int ld) {
  int l = threadIdx.x & 63;
  return *reinterpret_cast<const bf8*>(p + (l & 15) * ld + ((l >> 4) << 3));
}
__device__ inline f4 mfma16(bf8 a, bf8 b, f4 c) {
  return __builtin_amdgcn_mfma_f32_16x16x32_bf16(a, b, c, 0, 0, 0);
}
// async global->LDS, 16B per lane; LDS dest = base + lane*16 (wave-uniform base)
__device__ inline void gl2lds(const __bf16* g, __bf16* l) {
  __builtin_amdgcn_global_load_lds(
      (const __attribute__((address_space(1))) void*)g,
      (__attribute__((address_space(3))) void*)l, 16, 0, 0);
}

// ---- generic m97-style GEMM: C[M][N] = A[M][K](lda) x Bt[N][K](ldb)^T ------
// 128x128 tile, BK=32, 4 waves in 2x2.
// EPI: 0 = store fp32, 1 = store bf16, 3 = store fp32 + per-column softmax
// stats partials (max, sum-exp2 over this wave's 64 rows) into Pm/Pd[col][144]
template <int EPI>
__global__ __launch_bounds__(256) void gemm128(const __bf16* __restrict__ A, int lda,
                                               const __bf16* __restrict__ Bt, int ldb,
                                               void* __restrict__ Cv, int ldc, int K,
                                               float* __restrict__ Pm,
                                               float* __restrict__ Pd) {
  __shared__ __bf16 As[128 * 32];
  __shared__ __bf16 Bs[128 * 32];
  const int tid = threadIdx.x;
  const int w = tid >> 6, lane = tid & 63;
  const int lc = lane & 15, quad = lane >> 4;
  const int m0 = blockIdx.x * 128, n0 = blockIdx.y * 128;
  const int wm = (w & 1) << 6, wn = (w >> 1) << 6;
  // staging: wave w fills LDS chunks 2w, 2w+1 of A and B (16 rows x 32k each)
  const int r0 = (w * 2) * 16 + (lane >> 2);
  const int cg = (lane & 3) * 8;
  const __bf16* gA0 = A + (size_t)(m0 + r0) * lda + cg;
  const __bf16* gA1 = A + (size_t)(m0 + r0 + 16) * lda + cg;
  const __bf16* gB0 = Bt + (size_t)(n0 + r0) * ldb + cg;
  const __bf16* gB1 = Bt + (size_t)(n0 + r0 + 16) * ldb + cg;
  __bf16* lA0 = As + (w * 2) * 512;
  __bf16* lA1 = As + (w * 2 + 1) * 512;
  __bf16* lB0 = Bs + (w * 2) * 512;
  __bf16* lB1 = Bs + (w * 2 + 1) * 512;

  f4 acc[4][4] = {};
  for (int kk = 0; kk < K; kk += 32) {
    __syncthreads();
    gl2lds(gA0 + kk, lA0);
    gl2lds(gA1 + kk, lA1);
    gl2lds(gB0 + kk, lB0);
    gl2lds(gB1 + kk, lB1);
    __syncthreads();  // compiler drains vmcnt before s_barrier
    bf8 af[4], bfr[4];
    for (int i = 0; i < 4; i++) af[i] = ldfrag(As + (wm + 16 * i) * 32, 32);
    for (int j = 0; j < 4; j++) bfr[j] = ldfrag(Bs + (wn + 16 * j) * 32, 32);
    for (int i = 0; i < 4; i++)
      for (int j = 0; j < 4; j++) acc[i][j] = mfma16(af[i], bfr[j], acc[i][j]);
  }
  for (int i = 0; i < 4; i++)
    for (int j = 0; j < 4; j++)
      for (int r = 0; r < 4; r++) {
        size_t idx = (size_t)(m0 + wm + 16 * i + quad * 4 + r) * ldc +
                     (n0 + wn + 16 * j + lc);
        if (EPI == 1) ((__bf16*)Cv)[idx] = (__bf16)acc[i][j][r];
        else ((float*)Cv)[idx] = acc[i][j][r];
      }
  if (EPI == 3) {
    // per-column (kt) partial stats over this wave's 64 rows (q)
    const int mb = blockIdx.x * 2 + (w & 1);
    for (int j = 0; j < 4; j++) {
      float m = -1e30f;
      for (int i = 0; i < 4; i++)
        for (int r = 0; r < 4; r++) m = fmaxf(m, acc[i][j][r]);
      m = fmaxf(m, __shfl_xor(m, 16));
      m = fmaxf(m, __shfl_xor(m, 32));
      float d = 0.f;
      for (int i = 0; i < 4; i++)
        for (int r = 0; r < 4; r++) d += exp2f(acc[i][j][r] - m);
      d += __shfl_xor(d, 16);
      d += __shfl_xor(d, 32);
      if (quad == 0) {
        int col = n0 + wn + 16 * j + lc;
        Pm[(size_t)col * 144 + mb] = m;
        Pd[(size_t)col * 144 + mb] = d;
      }
    }
  }
}

// ---- prep: bf16 weights (Wq pre-scaled by log2e, fused QK), rel gather ----
__global__ __launch_bounds__(256) void prep_kernel(
    const float* Wq, const float* Wk, const float* Wv, const float* embd,
    const float* Wproj, const int* dist, const int* isWithin,
    __bf16* Wqkb, __bf16* Wvb, __bf16* Wpb, float* wl, __bf16* rel) {
  int tid = blockIdx.x * 256 + threadIdx.x;
  if (tid < 65536) {
    Wqkb[tid] = (__bf16)(Wq[tid] * LOG2E);  // rows 0..255: Q (exp2 domain)
    Wqkb[65536 + tid] = (__bf16)Wk[tid];    // rows 256..511: K
    Wvb[tid] = (__bf16)Wv[tid];
    int o = tid >> 8, c = tid & 255;
    Wpb[tid] = (__bf16)Wproj[o * 257 + c];
    if (c == 0) wl[o] = Wproj[o * 257 + 256];
  }
  if (tid < 16 * 256) {
    int z = tid >> 8, c = tid & 255;
    rel[tid] = (__bf16)embd[(isWithin[z] * 17 + dist[z] + 8) * 256 + c];
  }
}

// ---- transpose x [C,N] f32 -> Xt [N,C] bf16 -------------------------------
__global__ __launch_bounds__(256) void transpose_kernel(const float* x, __bf16* Xt) {
  __shared__ __bf16 tile[32][33];
  int n0 = blockIdx.x * 32;
  int c0 = blockIdx.y * 32;
  int tx = threadIdx.x & 31, ty = threadIdx.x >> 5;
  for (int i = 0; i < 32; i += 8)
    tile[ty + i][tx] = (__bf16)x[(c0 + ty + i) * NTOK + n0 + tx];
  __syncthreads();
  for (int i = 0; i < 32; i += 8)
    Xt[(n0 + ty + i) * CDIM + c0 + tx] = tile[tx][ty + i];
}

// ---- pos[16,9216] f32 = rel[16,256] x Xt[9216,256]^T ----------------------
__global__ __launch_bounds__(256) void gemm_pos(const __bf16* rel, const __bf16* Xt,
                                                float* pos) {
  int n0 = blockIdx.x * 256 + (threadIdx.x >> 6) * 64;
  f4 acc[4] = {};
  for (int ks = 0; ks < 256; ks += 32) {
    bf8 a = ldfrag(rel + ks, 256);
    for (int j = 0; j < 4; j++) {
      bf8 b = ldfrag(Xt + (n0 + 16 * j) * 256 + ks, 256);
      acc[j] = mfma16(a, b, acc[j]);
    }
  }
  int l = threadIdx.x & 63, lc = l & 15, quad = l >> 4;
  for (int j = 0; j < 4; j++)
    for (int r = 0; r < 4; r++)
      pos[(quad * 4 + r) * NTOK + n0 + 16 * j + lc] = acc[j][r];
}

// ---- LSE-merge of 144 per-block partials -> m_k, dinv_k (1 wave per kt) ---
__global__ __launch_bounds__(256) void combine_stats(const float* __restrict__ Pm,
                                                     const float* __restrict__ Pd,
                                                     float* mArr, float* dinv) {
  int kt = blockIdx.x * 4 + (threadIdx.x >> 6);
  int lane = threadIdx.x & 63;
  const float* pm = Pm + (size_t)kt * 144;
  const float* pd = Pd + (size_t)kt * 144;
  float m0 = pm[lane], m1 = pm[lane + 64];
  float m2 = (lane < 16) ? pm[lane + 128] : -1e30f;
  float d0 = pd[lane], d1 = pd[lane + 64];
  float d2 = (lane < 16) ? pd[lane + 128] : 0.f;
  float m = fmaxf(fmaxf(m0, m1), m2);
  for (int off = 1; off < 64; off <<= 1) m = fmaxf(m, __shfl_xor(m, off));
  float d = d0 * exp2f(m0 - m) + d1 * exp2f(m1 - m);
  if (lane < 16) d += d2 * exp2f(m2 - m);
  for (int off = 1; off < 64; off <<= 1) d += __shfl_xor(d, off);
  if (lane == 0) {
    mArr[kt] = m;
    dinv[kt] = 1.0f / d;
  }
}

// ---- V'[c][kt] = V[c][kt] * dinv[kt] (in place) ---------------------------
__global__ __launch_bounds__(256) void vscale_kernel(__bf16* V, const float* dinv) {
  size_t off = ((size_t)blockIdx.x * 256 + threadIdx.x) * 8;
  bf8 v = *reinterpret_cast<const bf8*>(V + off);
  int kt = (int)(off % NTOK);
  f4 dl = *reinterpret_cast<const f4*>(dinv + kt);
  f4 dh = *reinterpret_cast<const f4*>(dinv + kt + 4);
  bf8 o;
  for (int j = 0; j < 4; j++) o[j] = (__bf16)((float)v[j] * dl[j]);
  for (int j = 0; j < 4; j++) o[4 + j] = (__bf16)((float)v[4 + j] * dh[j]);
  *reinterpret_cast<bf8*>(V + off) = o;
}

// ---- fused PV: Ypart[z][q][c] = sum_kt exp2(S^T[q][kt]-m_kt) * V'[c][kt] ---
// block: 128 q x 256 c, waves 2x2 (wave tile 64 q x 128 c). Per K-step (32 kt):
// reg-stage S^T fp32 -> exp2 -> bf16 -> chunk-swizzled LDS A-tile; V' via
// global_load_lds (linear). A-tile swizzle: chunk' = chunk ^ (row&3), applied
// identically on write and read (involution).
__global__ __launch_bounds__(256, 2) void pv_kernel(const float* __restrict__ S,
                                                    const float* __restrict__ mArr,
                                                    const __bf16* __restrict__ Vp,
                                                    float* __restrict__ Ypart,
                                                    int nstep) {
  __shared__ __bf16 As[128 * 32];  // P~^T tile [q][kt], chunk-swizzled
  __shared__ __bf16 Bs[256 * 32];  // V' tile [c][kt]
  const int tid = threadIdx.x;
  const int w = tid >> 6, lane = tid & 63;
  const int lc = lane & 15, quad = lane >> 4;
  const int q0 = blockIdx.x * 128;
  const int z = blockIdx.y;
  const int wm = (w & 1) << 6;   // q-half within block
  const int wn = (w >> 1) << 7;  // c-half (128 wide)
  const int ktbase = z * nstep * 32;
  // A staging map: thread -> (row aq, 16-kt half ah)
  const int aq = tid >> 1, ah = (tid & 1) << 4;
  const float* Sg = S + (size_t)(q0 + aq) * NTOK + ktbase + ah;
  const float* Mg = mArr + ktbase + ah;
  const int ac0 = ah >> 3;  // logical chunk of first 8 kt (0 or 2)
  __bf16* aw0 = As + aq * 32 + ((ac0 ^ (aq & 3)) << 3);
  __bf16* aw1 = As + aq * 32 + (((ac0 + 1) ^ (aq & 3)) << 3);
  // B staging: wave w stages rows [w*64, w*64+64), 4 x gl2lds of 16 rows
  const __bf16* gB = Vp + (size_t)(w * 64 + (lane >> 2)) * NTOK + ktbase +
                     ((lane & 3) << 3);
  f4 acc[4][8] = {};
  for (int s = 0; s < nstep; s++) {
    const int kk = s * 32;
    __syncthreads();
    for (int u = 0; u < 4; u++)
      gl2lds(gB + (size_t)(16 * u) * NTOK + kk, Bs + (w * 64 + 16 * u) * 32);
    f4 sv0 = *reinterpret_cast<const f4*>(Sg + kk);
    f4 sv1 = *reinterpret_cast<const f4*>(Sg + kk + 4);
    f4 sv2 = *reinterpret_cast<const f4*>(Sg + kk + 8);
    f4 sv3 = *reinterpret_cast<const f4*>(Sg + kk + 12);
    f4 mv0 = *reinterpret_cast<const f4*>(Mg + kk);
    f4 mv1 = *reinterpret_cast<const f4*>(Mg + kk + 4);
    f4 mv2 = *reinterpret_cast<const f4*>(Mg + kk + 8);
    f4 mv3 = *reinterpret_cast<const f4*>(Mg + kk + 12);
    bf8 h0, h1;
    for (int j = 0; j < 4; j++) {
      h0[j] = (__bf16)exp2f(sv0[j] - mv0[j]);
      h0[4 + j] = (__bf16)exp2f(sv1[j] - mv1[j]);
      h1[j] = (__bf16)exp2f(sv2[j] - mv2[j]);
      h1[4 + j] = (__bf16)exp2f(sv3[j] - mv3[j]);
    }
    *reinterpret_cast<bf8*>(aw0) = h0;
    *reinterpret_cast<bf8*>(aw1) = h1;
    __syncthreads();
    bf8 af[4], bfr[8];
    for (int i = 0; i < 4; i++)
      af[i] = *reinterpret_cast<const bf8*>(As + (wm + 16 * i + lc) * 32 +
                                            ((quad ^ (lc & 3)) << 3));
    for (int j = 0; j < 8; j++) bfr[j] = ldfrag(Bs + (wn + 16 * j) * 32, 32);
    for (int i = 0; i < 4; i++)
      for (int j = 0; j < 8; j++) acc[i][j] = mfma16(af[i], bfr[j], acc[i][j]);
  }
  float* Yp = Ypart + (size_t)z * NTOK * 256;
  for (int i = 0; i < 4; i++)
    for (int j = 0; j < 8; j++)
      for (int r = 0; r < 4; r++)
        Yp[(size_t)(q0 + wm + 16 * i + quad * 4 + r) * 256 + wn + 16 * j + lc] =
            acc[i][j][r];
}

// ---- combine zp Y-partials + residual -> outT [N,C] bf16 ------------------
__global__ __launch_bounds__(256) void combine_y_kernel(const float* __restrict__ Ypart,
                                                        const __bf16* __restrict__ Xt,
                                                        __bf16* outT, int zp) {
  int i = blockIdx.x * 256 + threadIdx.x;
  f4 y = {};
  for (int z = 0; z < zp; z++) {
    f4 p = reinterpret_cast<const f4*>(Ypart + (size_t)z * NTOK * 256)[i];
    for (int t = 0; t < 4; t++) y[t] += p[t];
  }
  bfx4 xv = reinterpret_cast<const bfx4*>(Xt)[i];
  bfx4 o;
  for (int t = 0; t < 4; t++) o[t] = (__bf16)(y[t] + (float)xv[t]);
  reinterpret_cast<bfx4*>(outT)[i] = o;
}

// ---- final: out[z,o,n] = base[o,n] + wl[o]*pos[z,n] -----------------------
__global__ __launch_bounds__(256) void final_kernel(const float* base, const float* pos,
                                                    const float* wl, float* out) {
  int i = blockIdx.x * 256 + threadIdx.x;
  int n4 = i % 2304;
  int t = i / 2304;
  int o = t & 255;
  int z = t >> 8;
  f4 b = reinterpret_cast<const f4*>(base)[o * 2304 + n4];
  f4 p = reinterpret_cast<const f4*>(pos)[z * 2304 + n4];
  float ww = wl[o];
  f4 r;
  for (int u = 0; u < 4; u++) r[u] = b[u] + ww * p[u];
  reinterpret_cast<f4*>(out)[i] = r;
}

extern "C" void kernel_launch(void* const* d_in, const int* in_sizes, int n_in,
                              void* d_out, int out_size, void* d_ws, size_t ws_size,
                              hipStream_t stream) {
  const float* x = (const float*)d_in[0];
  const float* Wq = (const float*)d_in[1];
  const float* Wk = (const float*)d_in[2];
  const float* Wv = (const float*)d_in[3];
  const float* embd = (const float*)d_in[4];
  const float* Wproj = (const float*)d_in[5];
  const int* dist = (const int*)d_in[6];
  const int* isW = (const int*)d_in[7];
  float* out = (float*)d_out;

  char* w8 = (char*)d_ws;
  __bf16* Xt = (__bf16*)(w8 + 0);            // 4,718,592
  __bf16* QKt = (__bf16*)(w8 + 4718592);     // 9,437,184 [q][512]: Q|K
  __bf16* V = (__bf16*)(w8 + 14155776);      // 4,718,592 [c][n] (scaled in place)
  __bf16* Wqkb = (__bf16*)(w8 + 18874368);   // 262,144
  __bf16* Wvb = (__bf16*)(w8 + 19136512);    // 131,072
  __bf16* Wpb = (__bf16*)(w8 + 19267584);    // 131,072
  __bf16* rel = (__bf16*)(w8 + 19398656);    // 8,192
  float* wl = (float*)(w8 + 19406848);       // 1,024
  float* pos = (float*)(w8 + 19407872);      // 589,824
  float* mArr = (float*)(w8 + 19997696);     // 36,864
  float* dinv = (float*)(w8 + 20034560);     // 36,864
  const size_t sOff = 29508608;
  float* S = (float*)(w8 + sOff);            // 339,738,624  S^T[q][kt] fp32
  float* Pm = (float*)(w8 + sOff + 339738624);             // 5,308,416
  float* Pd = (float*)(w8 + sOff + 339738624 + 5308416);   // 5,308,416
  const size_t ypOff = sOff + 339738624 + 2 * 5308416;     // 380,355,584... base
  float* Ypart = (float*)(w8 + ypOff);       // zp * 9,437,184
  __bf16* outT = (__bf16*)(w8 + sOff);       // alias S (dead by then)
  float* base = (float*)(w8 + sOff + 4718592);

  // pick kt-split so Ypart fits (ws_size constant across calls -> graph-safe);
  // measured harness ws >= 539 MB so zp=8 is the expected branch
  static const int ZPS[] = {8, 6, 4, 3, 2, 1};
  int zp = 1;
  for (int i = 0; i < 6; i++)
    if (ypOff + (size_t)ZPS[i] * 9437184 <= ws_size) { zp = ZPS[i]; break; }

  prep_kernel<<<256, 256, 0, stream>>>(Wq, Wk, Wv, embd, Wproj, dist, isW,
                                       Wqkb, Wvb, Wpb, wl, rel);
  transpose_kernel<<<dim3(288, 8), 256, 0, stream>>>(x, Xt);
  // QK fused: QKt[9216][512] = Xt x Wqkb^T
  gemm128<1><<<dim3(72, 4), 256, 0, stream>>>(Xt, 256, Wqkb, 256, QKt, 512, 256,
                                              nullptr, nullptr);
  // V[256][9216] = Wvb x Xt^T
  gemm128<1><<<dim3(2, 72), 256, 0, stream>>>(Wvb, 256, Xt, 256, V, NTOK, 256,
                                              nullptr, nullptr);
  gemm_pos<<<36, 256, 0, stream>>>(rel, Xt, pos);
  // S^T[q][kt] = Qt x Kt^T (fp32, log2 domain) + fused per-kt stats partials
  gemm128<3><<<dim3(72, 72), 256, 0, stream>>>(QKt, 512, QKt + 256, 512, S, NTOK,
                                               256, Pm, Pd);
  combine_stats<<<2304, 256, 0, stream>>>(Pm, Pd, mArr, dinv);
  vscale_kernel<<<1152, 256, 0, stream>>>(V, dinv);
  pv_kernel<<<dim3(72, zp), 256, 0, stream>>>(S, mArr, V, Ypart, 288 / zp);
  combine_y_kernel<<<2304, 256, 0, stream>>>(Ypart, Xt, outT, zp);
  // base[o][n] = Wpb x outT^T
  gemm128<0><<<dim3(2, 72), 256, 0, stream>>>(Wpb, 256, outT, 256, base, NTOK, 256,
                                              nullptr, nullptr);
  final_kernel<<<36864, 256, 0, stream>>>(base, pos, wl, out);
}

// Round 3
// 447.269 us; speedup vs baseline: 1.3244x; 1.1685x over previous
//
#include <hip/hip_runtime.h>
#include <hip/hip_bf16.h>

typedef __bf16 bf8 __attribute__((ext_vector_type(8)));
typedef __bf16 bfx4 __attribute__((ext_vector_type(4)));
typedef float f4 __attribute__((ext_vector_type(4)));

#define NTOK 9216
#define CDIM 256
#define LOG2E 1.44269504f

// ---- MFMA fragment helpers (16x16x32 bf16) --------------------------------
// A[m][k]: lane m=l&15, k=(l>>4)*8+j ; Bt[n][k] same ; D: row=(l>>4)*4+reg,
// col=l&15
__device__ inline bf8 ldfrag(const __bf16* p, int ld) {
  int l = threadIdx.x & 63;
  return *reinterpret_cast<const bf8*>(p + (l & 15) * ld + ((l >> 4) << 3));
}
__device__ inline f4 mfma16(bf8 a, bf8 b, f4 c) {
  return __builtin_amdgcn_mfma_f32_16x16x32_bf16(a, b, c, 0, 0, 0);
}
// async global->LDS, 16B per lane; LDS dest = base + lane*16 (wave-uniform base)
__device__ inline void gl2lds(const __bf16* g, __bf16* l) {
  __builtin_amdgcn_global_load_lds(
      (const __attribute__((address_space(1))) void*)g,
      (__attribute__((address_space(3))) void*)l, 16, 0, 0);
}

// ---- generic m97-style GEMM: C[M][N] = A[M][K](lda) x Bt[N][K](ldb)^T ------
// 128x128 tile, BK=32, 4 waves in 2x2.
// EPI: 0 = store fp32, 1 = store bf16, 3 = store fp32 into kt-tiled layout
// S[((col>>7)*NTOK + row)*128 + (col&127)] + per-column softmax stats partials
// (max, sum-exp2 over this wave's 64 rows) into Pm/Pd[col][144]
template <int EPI>
__global__ __launch_bounds__(256) void gemm128(const __bf16* __restrict__ A, int lda,
                                               const __bf16* __restrict__ Bt, int ldb,
                                               void* __restrict__ Cv, int ldc, int K,
                                               float* __restrict__ Pm,
                                               float* __restrict__ Pd) {
  __shared__ __bf16 As[128 * 32];
  __shared__ __bf16 Bs[128 * 32];
  const int tid = threadIdx.x;
  const int w = tid >> 6, lane = tid & 63;
  const int lc = lane & 15, quad = lane >> 4;
  const int m0 = blockIdx.x * 128, n0 = blockIdx.y * 128;
  const int wm = (w & 1) << 6, wn = (w >> 1) << 6;
  // staging: wave w fills LDS chunks 2w, 2w+1 of A and B (16 rows x 32k each)
  const int r0 = (w * 2) * 16 + (lane >> 2);
  const int cg = (lane & 3) * 8;
  const __bf16* gA0 = A + (size_t)(m0 + r0) * lda + cg;
  const __bf16* gA1 = A + (size_t)(m0 + r0 + 16) * lda + cg;
  const __bf16* gB0 = Bt + (size_t)(n0 + r0) * ldb + cg;
  const __bf16* gB1 = Bt + (size_t)(n0 + r0 + 16) * ldb + cg;
  __bf16* lA0 = As + (w * 2) * 512;
  __bf16* lA1 = As + (w * 2 + 1) * 512;
  __bf16* lB0 = Bs + (w * 2) * 512;
  __bf16* lB1 = Bs + (w * 2 + 1) * 512;

  f4 acc[4][4] = {};
  for (int kk = 0; kk < K; kk += 32) {
    __syncthreads();
    gl2lds(gA0 + kk, lA0);
    gl2lds(gA1 + kk, lA1);
    gl2lds(gB0 + kk, lB0);
    gl2lds(gB1 + kk, lB1);
    __syncthreads();  // compiler drains vmcnt before s_barrier
    bf8 af[4], bfr[4];
    for (int i = 0; i < 4; i++) af[i] = ldfrag(As + (wm + 16 * i) * 32, 32);
    for (int j = 0; j < 4; j++) bfr[j] = ldfrag(Bs + (wn + 16 * j) * 32, 32);
    for (int i = 0; i < 4; i++)
      for (int j = 0; j < 4; j++) acc[i][j] = mfma16(af[i], bfr[j], acc[i][j]);
  }
  if (EPI == 3) {
    for (int i = 0; i < 4; i++)
      for (int j = 0; j < 4; j++)
        for (int r = 0; r < 4; r++) {
          int row = m0 + wm + 16 * i + quad * 4 + r;
          int col = n0 + wn + 16 * j + lc;
          ((float*)Cv)[((size_t)(col >> 7) * NTOK + row) * 128 + (col & 127)] =
              acc[i][j][r];
        }
    // per-column (kt) partial stats over this wave's 64 rows (q)
    const int mb = blockIdx.x * 2 + (w & 1);
    for (int j = 0; j < 4; j++) {
      float m = -1e30f;
      for (int i = 0; i < 4; i++)
        for (int r = 0; r < 4; r++) m = fmaxf(m, acc[i][j][r]);
      m = fmaxf(m, __shfl_xor(m, 16));
      m = fmaxf(m, __shfl_xor(m, 32));
      float d = 0.f;
      for (int i = 0; i < 4; i++)
        for (int r = 0; r < 4; r++) d += exp2f(acc[i][j][r] - m);
      d += __shfl_xor(d, 16);
      d += __shfl_xor(d, 32);
      if (quad == 0) {
        int col = n0 + wn + 16 * j + lc;
        Pm[(size_t)col * 144 + mb] = m;
        Pd[(size_t)col * 144 + mb] = d;
      }
    }
  } else {
    for (int i = 0; i < 4; i++)
      for (int j = 0; j < 4; j++)
        for (int r = 0; r < 4; r++) {
          size_t idx = (size_t)(m0 + wm + 16 * i + quad * 4 + r) * ldc +
                       (n0 + wn + 16 * j + lc);
          if (EPI == 1) ((__bf16*)Cv)[idx] = (__bf16)acc[i][j][r];
          else ((float*)Cv)[idx] = acc[i][j][r];
        }
  }
}

// ---- prep: bf16 weights (Wq pre-scaled by log2e, fused QK), rel gather ----
__global__ __launch_bounds__(256) void prep_kernel(
    const float* Wq, const float* Wk, const float* Wv, const float* embd,
    const float* Wproj, const int* dist, const int* isWithin,
    __bf16* Wqkb, __bf16* Wvb, __bf16* Wpb, float* wl, __bf16* rel) {
  int tid = blockIdx.x * 256 + threadIdx.x;
  if (tid < 65536) {
    Wqkb[tid] = (__bf16)(Wq[tid] * LOG2E);  // rows 0..255: Q (exp2 domain)
    Wqkb[65536 + tid] = (__bf16)Wk[tid];    // rows 256..511: K
    Wvb[tid] = (__bf16)Wv[tid];
    int o = tid >> 8, c = tid & 255;
    Wpb[tid] = (__bf16)Wproj[o * 257 + c];
    if (c == 0) wl[o] = Wproj[o * 257 + 256];
  }
  if (tid < 16 * 256) {
    int z = tid >> 8, c = tid & 255;
    rel[tid] = (__bf16)embd[(isWithin[z] * 17 + dist[z] + 8) * 256 + c];
  }
}

// ---- transpose x [C,N] f32 -> Xt [N,C] bf16 -------------------------------
__global__ __launch_bounds__(256) void transpose_kernel(const float* x, __bf16* Xt) {
  __shared__ __bf16 tile[32][33];
  int n0 = blockIdx.x * 32;
  int c0 = blockIdx.y * 32;
  int tx = threadIdx.x & 31, ty = threadIdx.x >> 5;
  for (int i = 0; i < 32; i += 8)
    tile[ty + i][tx] = (__bf16)x[(c0 + ty + i) * NTOK + n0 + tx];
  __syncthreads();
  for (int i = 0; i < 32; i += 8)
    Xt[(n0 + ty + i) * CDIM + c0 + tx] = tile[tx][ty + i];
}

// ---- pos[16,9216] f32 = rel[16,256] x Xt[9216,256]^T ----------------------
__global__ __launch_bounds__(256) void gemm_pos(const __bf16* rel, const __bf16* Xt,
                                                float* pos) {
  int n0 = blockIdx.x * 256 + (threadIdx.x >> 6) * 64;
  f4 acc[4] = {};
  for (int ks = 0; ks < 256; ks += 32) {
    bf8 a = ldfrag(rel + ks, 256);
    for (int j = 0; j < 4; j++) {
      bf8 b = ldfrag(Xt + (n0 + 16 * j) * 256 + ks, 256);
      acc[j] = mfma16(a, b, acc[j]);
    }
  }
  int l = threadIdx.x & 63, lc = l & 15, quad = l >> 4;
  for (int j = 0; j < 4; j++)
    for (int r = 0; r < 4; r++)
      pos[(quad * 4 + r) * NTOK + n0 + 16 * j + lc] = acc[j][r];
}

// ---- LSE-merge of 144 per-block partials -> m_k, dinv_k (1 wave per kt) ---
__global__ __launch_bounds__(256) void combine_stats(const float* __restrict__ Pm,
                                                     const float* __restrict__ Pd,
                                                     float* mArr, float* dinv) {
  int kt = blockIdx.x * 4 + (threadIdx.x >> 6);
  int lane = threadIdx.x & 63;
  const float* pm = Pm + (size_t)kt * 144;
  const float* pd = Pd + (size_t)kt * 144;
  float m0 = pm[lane], m1 = pm[lane + 64];
  float m2 = (lane < 16) ? pm[lane + 128] : -1e30f;
  float d0 = pd[lane], d1 = pd[lane + 64];
  float d2 = (lane < 16) ? pd[lane + 128] : 0.f;
  float m = fmaxf(fmaxf(m0, m1), m2);
  for (int off = 1; off < 64; off <<= 1) m = fmaxf(m, __shfl_xor(m, off));
  float d = d0 * exp2f(m0 - m) + d1 * exp2f(m1 - m);
  if (lane < 16) d += d2 * exp2f(m2 - m);
  for (int off = 1; off < 64; off <<= 1) d += __shfl_xor(d, off);
  if (lane == 0) {
    mArr[kt] = m;
    dinv[kt] = 1.0f / d;
  }
}

// ---- V'[c][kt] = V[c][kt] * dinv[kt] (in place) ---------------------------
__global__ __launch_bounds__(256) void vscale_kernel(__bf16* V, const float* dinv) {
  size_t off = ((size_t)blockIdx.x * 256 + threadIdx.x) * 8;
  bf8 v = *reinterpret_cast<const bf8*>(V + off);
  int kt = (int)(off % NTOK);
  f4 dl = *reinterpret_cast<const f4*>(dinv + kt);
  f4 dh = *reinterpret_cast<const f4*>(dinv + kt + 4);
  bf8 o;
  for (int j = 0; j < 4; j++) o[j] = (__bf16)((float)v[j] * dl[j]);
  for (int j = 0; j < 4; j++) o[4 + j] = (__bf16)((float)v[4 + j] * dh[j]);
  *reinterpret_cast<bf8*>(V + off) = o;
}

// ---- fused PV: Ypart[z][q][c] = sum_kt exp2(S[q][kt]-m_kt) * V'[c][kt] -----
// S is kt-tiled: elem (q,kt) at S[((kt>>7)*NTOK + q)*128 + (kt&127)].
// block: 128 q x 256 c, waves 2x2. Deep pipeline: LDS dbuf (A,B), 2-deep reg
// prefetch of S, counted vmcnt barrier (4 S-loads stay in flight across it).
template <int NSTEP>
__global__ __launch_bounds__(256, 2) void pv_kernel(const float* __restrict__ S,
                                                    const float* __restrict__ mArr,
                                                    const __bf16* __restrict__ Vp,
                                                    float* __restrict__ Ypart) {
  __shared__ __bf16 As[2][128 * 32];
  __shared__ __bf16 Bs[2][256 * 32];
  __shared__ float ms_l[(NSTEP + 1) * 32];
  const int tid = threadIdx.x;
  const int w = tid >> 6, lane = tid & 63;
  const int lc = lane & 15, quad = lane >> 4;
  const int q0 = blockIdx.x * 128;
  const int z = blockIdx.y;
  const int wm = (w & 1) << 6;   // q-half within block
  const int wn = (w >> 1) << 7;  // c-half (128 wide)
  const int ktbase = z * NSTEP * 32;
  const int ktb0 = ktbase >> 7;
  const int aq = tid >> 1, ah = (tid & 1) << 4;
  const float* Sb = S + (size_t)(q0 + aq) * 128 + ah;
  const int ac0 = ah >> 3;
  const int sw0 = (ac0 ^ (aq & 3)) << 3;
  const int sw1 = ((ac0 + 1) ^ (aq & 3)) << 3;
  const __bf16* gB =
      Vp + (size_t)(w * 64 + (lane >> 2)) * NTOK + ktbase + ((lane & 3) << 3);

  // stage m slice (+1 step of slack for the dead tail prefetch) into LDS
  for (int i = tid * 4; i < (NSTEP + 1) * 32; i += 1024)
    *reinterpret_cast<f4*>(&ms_l[i]) =
        *reinterpret_cast<const f4*>(mArr + ktbase + i);

  // prologue: B(0)->Bs[0]; S(0)->T; S(1)->X; exp T -> As[0]
  for (int u = 0; u < 4; u++)
    gl2lds(gB + (size_t)(16 * u) * NTOK, &Bs[0][(w * 64 + 16 * u) * 32]);
  const float* Sp0 = Sb + (size_t)ktb0 * (NTOK * 128);
  f4 T0 = *reinterpret_cast<const f4*>(Sp0);
  f4 T1 = *reinterpret_cast<const f4*>(Sp0 + 4);
  f4 T2 = *reinterpret_cast<const f4*>(Sp0 + 8);
  f4 T3 = *reinterpret_cast<const f4*>(Sp0 + 12);
  f4 X0 = *reinterpret_cast<const f4*>(Sp0 + 32);
  f4 X1 = *reinterpret_cast<const f4*>(Sp0 + 36);
  f4 X2 = *reinterpret_cast<const f4*>(Sp0 + 40);
  f4 X3 = *reinterpret_cast<const f4*>(Sp0 + 44);
  f4 Y0, Y1, Y2, Y3;
  __syncthreads();
  {
    f4 m0 = *reinterpret_cast<const f4*>(&ms_l[ah]);
    f4 m1 = *reinterpret_cast<const f4*>(&ms_l[ah + 4]);
    f4 m2 = *reinterpret_cast<const f4*>(&ms_l[ah + 8]);
    f4 m3 = *reinterpret_cast<const f4*>(&ms_l[ah + 12]);
    bf8 h0, h1;
    for (int j = 0; j < 4; j++) {
      h0[j] = (__bf16)exp2f(T0[j] - m0[j]);
      h0[4 + j] = (__bf16)exp2f(T1[j] - m1[j]);
      h1[j] = (__bf16)exp2f(T2[j] - m2[j]);
      h1[4 + j] = (__bf16)exp2f(T3[j] - m3[j]);
    }
    *reinterpret_cast<bf8*>(&As[0][aq * 32 + sw0]) = h0;
    *reinterpret_cast<bf8*>(&As[0][aq * 32 + sw1]) = h1;
  }
  __syncthreads();

  f4 acc[4][8] = {};

// one K-step: MFMA on buf CUR; exp(XP = S(s+1)) -> As[CUR^1]; issue B(s+1)
// gl2lds and YP = S(s+2) loads; counted-vmcnt barrier keeps YP in flight.
#define PV_HALF(s, CUR, XP, YP)                                                \
  {                                                                            \
    const int kk1 = ((s) + 1) * 32;                                            \
    for (int u = 0; u < 4; u++)                                                \
      gl2lds(gB + (size_t)(16 * u) * NTOK + kk1,                               \
             &Bs[CUR ^ 1][(w * 64 + 16 * u) * 32]);                            \
    __builtin_amdgcn_sched_barrier(0);                                         \
    const float* Sp = Sb + (size_t)(ktb0 + (((s) + 2) >> 2)) * (NTOK * 128) +  \
                      (((s) + 2) & 3) * 32;                                    \
    YP##0 = *reinterpret_cast<const f4*>(Sp);                                  \
    YP##1 = *reinterpret_cast<const f4*>(Sp + 4);                              \
    YP##2 = *reinterpret_cast<const f4*>(Sp + 8);                              \
    YP##3 = *reinterpret_cast<const f4*>(Sp + 12);                             \
    __builtin_amdgcn_sched_barrier(0);                                         \
    bf8 af[4], bfr[8];                                                         \
    for (int i = 0; i < 4; i++)                                                \
      af[i] = *reinterpret_cast<const bf8*>(                                   \
          &As[CUR][(wm + 16 * i + lc) * 32 + ((quad ^ (lc & 3)) << 3)]);       \
    for (int j = 0; j < 8; j++)                                                \
      bfr[j] = ldfrag(&Bs[CUR][(wn + 16 * j) * 32], 32);                       \
    for (int i = 0; i < 4; i++)                                                \
      for (int j = 0; j < 8; j++)                                              \
        acc[i][j] = mfma16(af[i], bfr[j], acc[i][j]);                          \
    f4 m0 = *reinterpret_cast<const f4*>(&ms_l[kk1 + ah]);                     \
    f4 m1 = *reinterpret_cast<const f4*>(&ms_l[kk1 + ah + 4]);                 \
    f4 m2 = *reinterpret_cast<const f4*>(&ms_l[kk1 + ah + 8]);                 \
    f4 m3 = *reinterpret_cast<const f4*>(&ms_l[kk1 + ah + 12]);                \
    bf8 h0, h1;                                                                \
    for (int j = 0; j < 4; j++) {                                              \
      h0[j] = (__bf16)exp2f(XP##0[j] - m0[j]);                                 \
      h0[4 + j] = (__bf16)exp2f(XP##1[j] - m1[j]);                             \
      h1[j] = (__bf16)exp2f(XP##2[j] - m2[j]);                                 \
      h1[4 + j] = (__bf16)exp2f(XP##3[j] - m3[j]);                             \
    }                                                                          \
    *reinterpret_cast<bf8*>(&As[CUR ^ 1][aq * 32 + sw0]) = h0;                 \
    *reinterpret_cast<bf8*>(&As[CUR ^ 1][aq * 32 + sw1]) = h1;                 \
    asm volatile("s_waitcnt vmcnt(4) lgkmcnt(0)" ::: "memory");                \
    __builtin_amdgcn_sched_barrier(0);                                         \
    __builtin_amdgcn_s_barrier();                                              \
    __builtin_amdgcn_sched_barrier(0);                                         \
  }

  for (int s = 0; s < NSTEP; s += 2) {
    PV_HALF(s, 0, X, Y);
    PV_HALF(s + 1, 1, Y, X);
  }
#undef PV_HALF

  float* Yp = Ypart + (size_t)z * NTOK * 256;
  for (int i = 0; i < 4; i++)
    for (int j = 0; j < 8; j++)
      for (int r = 0; r < 4; r++)
        Yp[(size_t)(q0 + wm + 16 * i + quad * 4 + r) * 256 + wn + 16 * j + lc] =
            acc[i][j][r];
}

// ---- combine zp Y-partials + residual -> outT [N,C] bf16 ------------------
__global__ __launch_bounds__(256) void combine_y_kernel(const float* __restrict__ Ypart,
                                                        const __bf16* __restrict__ Xt,
                                                        __bf16* outT, int zp) {
  int i = blockIdx.x * 256 + threadIdx.x;
  f4 y = {};
  for (int z = 0; z < zp; z++) {
    f4 p = reinterpret_cast<const f4*>(Ypart + (size_t)z * NTOK * 256)[i];
    for (int t = 0; t < 4; t++) y[t] += p[t];
  }
  bfx4 xv = reinterpret_cast<const bfx4*>(Xt)[i];
  bfx4 o;
  for (int t = 0; t < 4; t++) o[t] = (__bf16)(y[t] + (float)xv[t]);
  reinterpret_cast<bfx4*>(outT)[i] = o;
}

// ---- final: out[z,o,n] = base[o,n] + wl[o]*pos[z,n] -----------------------
__global__ __launch_bounds__(256) void final_kernel(const float* base, const float* pos,
                                                    const float* wl, float* out) {
  int i = blockIdx.x * 256 + threadIdx.x;
  int n4 = i % 2304;
  int t = i / 2304;
  int o = t & 255;
  int z = t >> 8;
  f4 b = reinterpret_cast<const f4*>(base)[o * 2304 + n4];
  f4 p = reinterpret_cast<const f4*>(pos)[z * 2304 + n4];
  float ww = wl[o];
  f4 r;
  for (int u = 0; u < 4; u++) r[u] = b[u] + ww * p[u];
  reinterpret_cast<f4*>(out)[i] = r;
}

extern "C" void kernel_launch(void* const* d_in, const int* in_sizes, int n_in,
                              void* d_out, int out_size, void* d_ws, size_t ws_size,
                              hipStream_t stream) {
  const float* x = (const float*)d_in[0];
  const float* Wq = (const float*)d_in[1];
  const float* Wk = (const float*)d_in[2];
  const float* Wv = (const float*)d_in[3];
  const float* embd = (const float*)d_in[4];
  const float* Wproj = (const float*)d_in[5];
  const int* dist = (const int*)d_in[6];
  const int* isW = (const int*)d_in[7];
  float* out = (float*)d_out;

  char* w8 = (char*)d_ws;
  __bf16* Xt = (__bf16*)(w8 + 0);            // 4,718,592
  __bf16* QKt = (__bf16*)(w8 + 4718592);     // 9,437,184 [q][512]: Q|K
  __bf16* V = (__bf16*)(w8 + 14155776);      // 4,718,592 [c][n] (scaled in place)
  __bf16* Wqkb = (__bf16*)(w8 + 18874368);   // 262,144
  __bf16* Wvb = (__bf16*)(w8 + 19136512);    // 131,072
  __bf16* Wpb = (__bf16*)(w8 + 19267584);    // 131,072
  __bf16* rel = (__bf16*)(w8 + 19398656);    // 8,192
  float* wl = (float*)(w8 + 19406848);       // 1,024
  float* pos = (float*)(w8 + 19407872);      // 589,824
  float* mArr = (float*)(w8 + 19997696);     // 36,864
  float* dinv = (float*)(w8 + 20034560);     // 36,864
  const size_t sOff = 29508608;
  float* S = (float*)(w8 + sOff);            // 339,738,624  kt-tiled S
  float* Pm = (float*)(w8 + sOff + 339738624);             // 5,308,416
  float* Pd = (float*)(w8 + sOff + 339738624 + 5308416);   // 5,308,416
  const size_t ypOff = sOff + 339738624 + 2 * 5308416;     // Ypart base
  float* Ypart = (float*)(w8 + ypOff);       // zp * 9,437,184
  __bf16* outT = (__bf16*)(w8 + sOff);       // alias S (dead by then)
  float* base = (float*)(w8 + sOff + 4718592);

  // pick kt-split so Ypart fits (ws_size constant across calls -> graph-safe);
  // zp=6 preferred: 432 blocks all co-resident at 2/CU, minimal partial traffic
  static const int ZPS[] = {6, 4, 3, 2, 1};
  int zp = 1;
  for (int i = 0; i < 5; i++)
    if (ypOff + (size_t)ZPS[i] * 9437184 <= ws_size) { zp = ZPS[i]; break; }

  prep_kernel<<<256, 256, 0, stream>>>(Wq, Wk, Wv, embd, Wproj, dist, isW,
                                       Wqkb, Wvb, Wpb, wl, rel);
  transpose_kernel<<<dim3(288, 8), 256, 0, stream>>>(x, Xt);
  // QK fused: QKt[9216][512] = Xt x Wqkb^T
  gemm128<1><<<dim3(72, 4), 256, 0, stream>>>(Xt, 256, Wqkb, 256, QKt, 512, 256,
                                              nullptr, nullptr);
  // V[256][9216] = Wvb x Xt^T
  gemm128<1><<<dim3(2, 72), 256, 0, stream>>>(Wvb, 256, Xt, 256, V, NTOK, 256,
                                              nullptr, nullptr);
  gemm_pos<<<36, 256, 0, stream>>>(rel, Xt, pos);
  // S (kt-tiled) = Qt x Kt^T (fp32, log2 domain) + fused per-kt stats partials
  gemm128<3><<<dim3(72, 72), 256, 0, stream>>>(QKt, 512, QKt + 256, 512, S, NTOK,
                                               256, Pm, Pd);
  combine_stats<<<2304, 256, 0, stream>>>(Pm, Pd, mArr, dinv);
  vscale_kernel<<<1152, 256, 0, stream>>>(V, dinv);
  switch (zp) {
    case 6: pv_kernel<48><<<dim3(72, 6), 256, 0, stream>>>(S, mArr, V, Ypart); break;
    case 4: pv_kernel<72><<<dim3(72, 4), 256, 0, stream>>>(S, mArr, V, Ypart); break;
    case 3: pv_kernel<96><<<dim3(72, 3), 256, 0, stream>>>(S, mArr, V, Ypart); break;
    case 2: pv_kernel<144><<<dim3(72, 2), 256, 0, stream>>>(S, mArr, V, Ypart); break;
    default: pv_kernel<288><<<dim3(72, 1), 256, 0, stream>>>(S, mArr, V, Ypart); break;
  }
  combine_y_kernel<<<2304, 256, 0, stream>>>(Ypart, Xt, outT, zp);
  // base[o][n] = Wpb x outT^T
  gemm128<0><<<dim3(2, 72), 256, 0, stream>>>(Wpb, 256, outT, 256, base, NTOK, 256,
                                              nullptr, nullptr);
  final_kernel<<<36864, 256, 0, stream>>>(base, pos, wl, out);
}

// Round 5
// 408.169 us; speedup vs baseline: 1.4513x; 1.0958x over previous
//
#include <hip/hip_runtime.h>
#include <hip/hip_bf16.h>

typedef __bf16 bf8 __attribute__((ext_vector_type(8)));
typedef __bf16 bfx4 __attribute__((ext_vector_type(4)));
typedef float f4 __attribute__((ext_vector_type(4)));

#define NTOK 9216
#define CDIM 256
#define LOG2E 1.44269504f
#define PSHIFT 32.0f

// ---- MFMA fragment helpers (16x16x32 bf16) --------------------------------
// A[m][k]: lane m=l&15, k=(l>>4)*8+j ; Bt[n][k] same ; D: row=(l>>4)*4+reg,
// col=l&15
__device__ inline bf8 ldfrag(const __bf16* p, int ld) {
  int l = threadIdx.x & 63;
  return *reinterpret_cast<const bf8*>(p + (l & 15) * ld + ((l >> 4) << 3));
}
__device__ inline f4 mfma16(bf8 a, bf8 b, f4 c) {
  return __builtin_amdgcn_mfma_f32_16x16x32_bf16(a, b, c, 0, 0, 0);
}
// async global->LDS, 16B per lane; LDS dest = base + lane*16 (wave-uniform base)
__device__ inline void gl2lds(const __bf16* g, __bf16* l) {
  __builtin_amdgcn_global_load_lds(
      (const __attribute__((address_space(1))) void*)g,
      (__attribute__((address_space(3))) void*)l, 16, 0, 0);
}

// ---- generic m97-style GEMM: C[M][N] = A[M][K](lda) x Bt[N][K](ldb)^T ------
// 128x128 tile, BK=32, 4 waves in 2x2.
// EPI: 1 = store bf16 row-major
//      3 = P-path: store bf16(exp2(acc-PSHIFT)) into step-tiled chunk-swizzled
//          layout P[((col>>5)*NTOK + row)*32 + ((c2^(row&3))<<3) + (col&7)]
//          + per-column sum partials into aux0[col][144]
//      4 = fused final: out[z][row][col] = acc + aux1[row]*aux0[z*NTOK+col]
template <int EPI>
__global__ __launch_bounds__(256) void gemm128(const __bf16* __restrict__ A, int lda,
                                               const __bf16* __restrict__ Bt, int ldb,
                                               void* __restrict__ Cv, int ldc, int K,
                                               const float* __restrict__ aux0,
                                               const float* __restrict__ aux1) {
  __shared__ __bf16 As[128 * 32];
  __shared__ __bf16 Bs[128 * 32];
  const int tid = threadIdx.x;
  const int w = tid >> 6, lane = tid & 63;
  const int lc = lane & 15, quad = lane >> 4;
  const int m0 = blockIdx.x * 128, n0 = blockIdx.y * 128;
  const int wm = (w & 1) << 6, wn = (w >> 1) << 6;
  // staging: wave w fills LDS chunks 2w, 2w+1 of A and B (16 rows x 32k each)
  const int r0 = (w * 2) * 16 + (lane >> 2);
  const int cg = (lane & 3) * 8;
  const __bf16* gA0 = A + (size_t)(m0 + r0) * lda + cg;
  const __bf16* gA1 = A + (size_t)(m0 + r0 + 16) * lda + cg;
  const __bf16* gB0 = Bt + (size_t)(n0 + r0) * ldb + cg;
  const __bf16* gB1 = Bt + (size_t)(n0 + r0 + 16) * ldb + cg;
  __bf16* lA0 = As + (w * 2) * 512;
  __bf16* lA1 = As + (w * 2 + 1) * 512;
  __bf16* lB0 = Bs + (w * 2) * 512;
  __bf16* lB1 = Bs + (w * 2 + 1) * 512;

  f4 acc[4][4] = {};
  for (int kk = 0; kk < K; kk += 32) {
    __syncthreads();
    gl2lds(gA0 + kk, lA0);
    gl2lds(gA1 + kk, lA1);
    gl2lds(gB0 + kk, lB0);
    gl2lds(gB1 + kk, lB1);
    __syncthreads();  // compiler drains vmcnt before s_barrier
    bf8 af[4], bfr[4];
    for (int i = 0; i < 4; i++) af[i] = ldfrag(As + (wm + 16 * i) * 32, 32);
    for (int j = 0; j < 4; j++) bfr[j] = ldfrag(Bs + (wn + 16 * j) * 32, 32);
    for (int i = 0; i < 4; i++)
      for (int j = 0; j < 4; j++) acc[i][j] = mfma16(af[i], bfr[j], acc[i][j]);
  }
  if (EPI == 3) {
    __bf16* Pp = (__bf16*)Cv;
    float* Pd = (float*)aux0;
    const int mb = blockIdx.x * 2 + (w & 1);
    for (int j = 0; j < 4; j++) {
      int col = n0 + wn + 16 * j + lc;
      int sb = col >> 5, c2 = (col >> 3) & 3, e3 = col & 7;
      float d = 0.f;
      for (int i = 0; i < 4; i++) {
        int qb = m0 + wm + 16 * i + quad * 4;
        for (int r = 0; r < 4; r++) {
          float e = exp2f(acc[i][j][r] - PSHIFT);
          d += e;
          Pp[((size_t)sb * NTOK + qb + r) * 32 + ((c2 ^ r) << 3) + e3] = (__bf16)e;
        }
      }
      d += __shfl_xor(d, 16);
      d += __shfl_xor(d, 32);
      if (quad == 0) Pd[(size_t)col * 144 + mb] = d;
    }
  } else if (EPI == 4) {
    float* outp = (float*)Cv;
    for (int i = 0; i < 4; i++)
      for (int r = 0; r < 4; r++) {
        int o = m0 + wm + 16 * i + quad * 4 + r;
        float wo = aux1[o];
        for (int j = 0; j < 4; j++) {
          int n = n0 + wn + 16 * j + lc;
          float b = acc[i][j][r];
          for (int z = 0; z < 16; z++)
            outp[((size_t)z * 256 + o) * NTOK + n] =
                b + wo * aux0[(size_t)z * NTOK + n];
        }
      }
  } else {
    for (int i = 0; i < 4; i++)
      for (int j = 0; j < 4; j++)
        for (int r = 0; r < 4; r++) {
          size_t idx = (size_t)(m0 + wm + 16 * i + quad * 4 + r) * ldc +
                       (n0 + wn + 16 * j + lc);
          ((__bf16*)Cv)[idx] = (__bf16)acc[i][j][r];
        }
  }
}

// ---- prep: bf16 weights (Wq pre-scaled by log2e, fused QK), rel gather ----
__global__ __launch_bounds__(256) void prep_kernel(
    const float* Wq, const float* Wk, const float* Wv, const float* embd,
    const float* Wproj, const int* dist, const int* isWithin,
    __bf16* Wqkb, __bf16* Wvb, __bf16* Wpb, float* wl, __bf16* rel) {
  int tid = blockIdx.x * 256 + threadIdx.x;
  if (tid < 65536) {
    Wqkb[tid] = (__bf16)(Wq[tid] * LOG2E);  // rows 0..255: Q (exp2 domain)
    Wqkb[65536 + tid] = (__bf16)Wk[tid];    // rows 256..511: K
    Wvb[tid] = (__bf16)Wv[tid];
    int o = tid >> 8, c = tid & 255;
    Wpb[tid] = (__bf16)Wproj[o * 257 + c];
    if (c == 0) wl[o] = Wproj[o * 257 + 256];
  }
  if (tid < 16 * 256) {
    int z = tid >> 8, c = tid & 255;
    rel[tid] = (__bf16)embd[(isWithin[z] * 17 + dist[z] + 8) * 256 + c];
  }
}

// ---- transpose x [C,N] f32 -> Xt [N,C] bf16 -------------------------------
__global__ __launch_bounds__(256) void transpose_kernel(const float* x, __bf16* Xt) {
  __shared__ __bf16 tile[32][33];
  int n0 = blockIdx.x * 32;
  int c0 = blockIdx.y * 32;
  int tx = threadIdx.x & 31, ty = threadIdx.x >> 5;
  for (int i = 0; i < 32; i += 8)
    tile[ty + i][tx] = (__bf16)x[(c0 + ty + i) * NTOK + n0 + tx];
  __syncthreads();
  for (int i = 0; i < 32; i += 8)
    Xt[(n0 + ty + i) * CDIM + c0 + tx] = tile[tx][ty + i];
}

// ---- pos[16,9216] f32 = rel[16,256] x Xt[9216,256]^T ----------------------
__global__ __launch_bounds__(256) void gemm_pos(const __bf16* rel, const __bf16* Xt,
                                                float* pos) {
  int n0 = blockIdx.x * 256 + (threadIdx.x >> 6) * 64;
  f4 acc[4] = {};
  for (int ks = 0; ks < 256; ks += 32) {
    bf8 a = ldfrag(rel + ks, 256);
    for (int j = 0; j < 4; j++) {
      bf8 b = ldfrag(Xt + (n0 + 16 * j) * 256 + ks, 256);
      acc[j] = mfma16(a, b, acc[j]);
    }
  }
  int l = threadIdx.x & 63, lc = l & 15, quad = l >> 4;
  for (int j = 0; j < 4; j++)
    for (int r = 0; r < 4; r++)
      pos[(quad * 4 + r) * NTOK + n0 + 16 * j + lc] = acc[j][r];
}

// ---- dinv_k = 1 / sum of 144 per-block partials (1 wave per kt) -----------
__global__ __launch_bounds__(256) void combine_stats(const float* __restrict__ Pd,
                                                     float* dinv) {
  int kt = blockIdx.x * 4 + (threadIdx.x >> 6);
  int lane = threadIdx.x & 63;
  const float* pd = Pd + (size_t)kt * 144;
  float d = pd[lane] + pd[lane + 64] + ((lane < 16) ? pd[lane + 128] : 0.f);
  for (int off = 1; off < 64; off <<= 1) d += __shfl_xor(d, off);
  if (lane == 0) dinv[kt] = 1.0f / d;
}

// ---- V'[c][kt] = V[c][kt] * dinv[kt], stored chunk-swizzled ---------------
// within each 32-kt group: chunk c2 (8 elems) stored at position c2^(c&3)
__global__ __launch_bounds__(256) void vscale_kernel(const __bf16* __restrict__ V,
                                                     const float* __restrict__ dinv,
                                                     __bf16* __restrict__ Vs) {
  size_t off = ((size_t)blockIdx.x * 256 + threadIdx.x) * 8;
  bf8 v = *reinterpret_cast<const bf8*>(V + off);
  int c = (int)(off / NTOK);
  int kt = (int)(off % NTOK);
  f4 dl = *reinterpret_cast<const f4*>(dinv + kt);
  f4 dh = *reinterpret_cast<const f4*>(dinv + kt + 4);
  bf8 o;
  for (int j = 0; j < 4; j++) o[j] = (__bf16)((float)v[j] * dl[j]);
  for (int j = 0; j < 4; j++) o[4 + j] = (__bf16)((float)v[4 + j] * dh[j]);
  int c2 = (kt >> 3) & 3;
  size_t dst = (size_t)c * NTOK + (kt & ~31) + (((c2 ^ (c & 3))) << 3);
  *reinterpret_cast<bf8*>(Vs + dst) = o;
}

// ---- pv: pure bf16 GEMM  Ypart[z][q][c] = P[q][kt] x V'[c][kt]^T ----------
// block 64q x 256c, 4 waves (1x4). 3-buffer gl2lds pipeline, counted vmcnt(5),
// barrier-then-issue ordering (race-free). P and V' content pre-swizzled;
// reads XOR chunk with quad^(lc&3).
template <int NSTEP>
__global__ __launch_bounds__(256) void pv_kernel(const __bf16* __restrict__ P,
                                                 const __bf16* __restrict__ Vp,
                                                 float* __restrict__ Ypart) {
  __shared__ __bf16 As[3][64 * 32];
  __shared__ __bf16 Bs[3][256 * 32];
  const int tid = threadIdx.x;
  const int w = tid >> 6, lane = tid & 63;
  const int lc = lane & 15, quad = lane >> 4;
  const int q0 = blockIdx.x * 64;
  const int z = blockIdx.y;
  const int wn = w << 6;
  const int sb0 = z * NSTEP;
  // A staging: step tile = 4KB at P + ((sb0+s)*NTOK + q0)*32; wave w -> 1KB
  const __bf16* gA = P + ((size_t)sb0 * NTOK + q0) * 32 + w * 512 + lane * 8;
  const size_t aStride = (size_t)NTOK * 32;
  // B staging: wave w rows [w*64, w*64+64), 4 x gl2lds of 16 rows x 32 kt
  const __bf16* gB = Vp + (size_t)(w * 64 + (lane >> 2)) * NTOK + sb0 * 32 +
                     ((lane & 3) << 3);

  // prologue: issue steps 0 and 1
  for (int p = 0; p < 2; p++) {
    gl2lds(gA + (size_t)p * aStride, &As[p][w * 512]);
    for (int u = 0; u < 4; u++)
      gl2lds(gB + (size_t)(16 * u) * NTOK + p * 32, &Bs[p][(w * 64 + 16 * u) * 32]);
  }

  f4 acc[4][4] = {};
  int cur = 0;
  const int swz = (quad ^ (lc & 3)) << 3;
  for (int s = 0; s < NSTEP; s++) {
    asm volatile("s_waitcnt vmcnt(5)" ::: "memory");
    __builtin_amdgcn_sched_barrier(0);
    __builtin_amdgcn_s_barrier();
    __builtin_amdgcn_sched_barrier(0);
    int sp = (s + 2 < NSTEP) ? s + 2 : NSTEP - 1;
    int nb = cur + 2;
    if (nb >= 3) nb -= 3;
    gl2lds(gA + (size_t)sp * aStride, &As[nb][w * 512]);
    for (int u = 0; u < 4; u++)
      gl2lds(gB + (size_t)(16 * u) * NTOK + sp * 32, &Bs[nb][(w * 64 + 16 * u) * 32]);
    __builtin_amdgcn_sched_barrier(0);
    bf8 af[4], bfr[4];
    for (int i = 0; i < 4; i++)
      af[i] = *reinterpret_cast<const bf8*>(&As[cur][(16 * i + lc) * 32 + swz]);
    for (int j = 0; j < 4; j++)
      bfr[j] = *reinterpret_cast<const bf8*>(&Bs[cur][(wn + 16 * j + lc) * 32 + swz]);
    for (int i = 0; i < 4; i++)
      for (int j = 0; j < 4; j++) acc[i][j] = mfma16(af[i], bfr[j], acc[i][j]);
    cur = cur + 1;
    if (cur >= 3) cur = 0;
  }

  float* Yp = Ypart + (size_t)z * NTOK * 256;
  for (int i = 0; i < 4; i++)
    for (int j = 0; j < 4; j++)
      for (int r = 0; r < 4; r++)
        Yp[(size_t)(q0 + 16 * i + quad * 4 + r) * 256 + wn + 16 * j + lc] =
            acc[i][j][r];
}

// ---- combine zp Y-partials + residual -> outT [N,C] bf16 ------------------
__global__ __launch_bounds__(256) void combine_y_kernel(const float* __restrict__ Ypart,
                                                        const __bf16* __restrict__ Xt,
                                                        __bf16* outT, int zp) {
  int i = blockIdx.x * 256 + threadIdx.x;
  f4 y = {};
  for (int z = 0; z < zp; z++) {
    f4 p = reinterpret_cast<const f4*>(Ypart + (size_t)z * NTOK * 256)[i];
    for (int t = 0; t < 4; t++) y[t] += p[t];
  }
  bfx4 xv = reinterpret_cast<const bfx4*>(Xt)[i];
  bfx4 o;
  for (int t = 0; t < 4; t++) o[t] = (__bf16)(y[t] + (float)xv[t]);
  reinterpret_cast<bfx4*>(outT)[i] = o;
}

extern "C" void kernel_launch(void* const* d_in, const int* in_sizes, int n_in,
                              void* d_out, int out_size, void* d_ws, size_t ws_size,
                              hipStream_t stream) {
  const float* x = (const float*)d_in[0];
  const float* Wq = (const float*)d_in[1];
  const float* Wk = (const float*)d_in[2];
  const float* Wv = (const float*)d_in[3];
  const float* embd = (const float*)d_in[4];
  const float* Wproj = (const float*)d_in[5];
  const int* dist = (const int*)d_in[6];
  const int* isW = (const int*)d_in[7];
  float* out = (float*)d_out;

  char* w8 = (char*)d_ws;
  __bf16* Xt = (__bf16*)(w8 + 0);            // 4,718,592
  __bf16* QKt = (__bf16*)(w8 + 4718592);     // 9,437,184 [q][512]: Q|K
  __bf16* V = (__bf16*)(w8 + 14155776);      // 4,718,592 [c][n] raw
  __bf16* Wqkb = (__bf16*)(w8 + 18874368);   // 262,144
  __bf16* Wvb = (__bf16*)(w8 + 19136512);    // 131,072
  __bf16* Wpb = (__bf16*)(w8 + 19267584);    // 131,072
  __bf16* rel = (__bf16*)(w8 + 19398656);    // 8,192
  float* wl = (float*)(w8 + 19406848);       // 1,024
  float* pos = (float*)(w8 + 19407872);      // 589,824
  float* dinv = (float*)(w8 + 20034560);     // 36,864
  __bf16* Vs = (__bf16*)(w8 + 20971520);     // 4,718,592 scaled+swizzled V'
  const size_t sOff = 29508608;
  __bf16* P = (__bf16*)(w8 + sOff);          // 169,869,312 step-tiled bf16 P
  float* Pd = (float*)(w8 + sOff + 171966464);              // 5,308,416 (+2MB pad)
  const size_t ypOff = sOff + 171966464 + 5308416;          // Ypart base
  float* Ypart = (float*)(w8 + ypOff);       // zp * 9,437,184
  __bf16* outT = (__bf16*)(w8 + sOff);       // alias P (dead after pv)

  // pick kt-split so Ypart fits (ws_size constant across calls -> graph-safe)
  static const int ZPS[] = {6, 4, 3, 2, 1};
  int zp = 1;
  for (int i = 0; i < 5; i++)
    if (ypOff + (size_t)ZPS[i] * 9437184 <= ws_size) { zp = ZPS[i]; break; }

  prep_kernel<<<256, 256, 0, stream>>>(Wq, Wk, Wv, embd, Wproj, dist, isW,
                                       Wqkb, Wvb, Wpb, wl, rel);
  transpose_kernel<<<dim3(288, 8), 256, 0, stream>>>(x, Xt);
  // QK fused: QKt[9216][512] = Xt x Wqkb^T
  gemm128<1><<<dim3(72, 4), 256, 0, stream>>>(Xt, 256, Wqkb, 256, QKt, 512, 256,
                                              nullptr, nullptr);
  // V[256][9216] = Wvb x Xt^T
  gemm128<1><<<dim3(2, 72), 256, 0, stream>>>(Wvb, 256, Xt, 256, V, NTOK, 256,
                                              nullptr, nullptr);
  gemm_pos<<<36, 256, 0, stream>>>(rel, Xt, pos);
  // P = bf16(exp2(Qt x Kt^T - 32)) step-tiled + per-kt sum partials
  gemm128<3><<<dim3(72, 72), 256, 0, stream>>>(QKt, 512, QKt + 256, 512, P, 0, 256,
                                               (const float*)Pd, nullptr);
  combine_stats<<<2304, 256, 0, stream>>>(Pd, dinv);
  vscale_kernel<<<1152, 256, 0, stream>>>(V, dinv, Vs);
  switch (zp) {
    case 6: pv_kernel<48><<<dim3(144, 6), 256, 0, stream>>>(P, Vs, Ypart); break;
    case 4: pv_kernel<72><<<dim3(144, 4), 256, 0, stream>>>(P, Vs, Ypart); break;
    case 3: pv_kernel<96><<<dim3(144, 3), 256, 0, stream>>>(P, Vs, Ypart); break;
    case 2: pv_kernel<144><<<dim3(144, 2), 256, 0, stream>>>(P, Vs, Ypart); break;
    default: pv_kernel<288><<<dim3(144, 1), 256, 0, stream>>>(P, Vs, Ypart); break;
  }
  combine_y_kernel<<<2304, 256, 0, stream>>>(Ypart, Xt, outT, zp);
  // fused: out[z][o][n] = (Wpb x outT^T)[o][n] + wl[o]*pos[z][n]
  gemm128<4><<<dim3(2, 72), 256, 0, stream>>>(Wpb, 256, outT, 256, out, NTOK, 256,
                                              pos, wl);
}